// Round 4
// baseline (466.700 us; speedup 1.0000x reference)
//
#include <hip/hip_runtime.h>
#include <hip/hip_bf16.h>
#include <stdint.h>

typedef short bf16x8 __attribute__((ext_vector_type(8)));
typedef float f32x4 __attribute__((ext_vector_type(4)));
typedef float f32x16 __attribute__((ext_vector_type(16)));
typedef unsigned int u32x2 __attribute__((ext_vector_type(2)));
typedef unsigned int u32x4 __attribute__((ext_vector_type(4)));

__device__ __forceinline__ unsigned short f2bf(float f) {
  union { float f; unsigned u; } x; x.f = f;
  unsigned r = x.u + 0x7FFFu + ((x.u >> 16) & 1u);
  return (unsigned short)(r >> 16);
}

__device__ __forceinline__ unsigned pk2bf(float a, float b) {
  union { __hip_bfloat162 h; unsigned u; } x;
  x.h = __float22bfloat162_rn(make_float2(a, b));
  return x.u;
}

typedef const __attribute__((address_space(1))) unsigned int* gptr_t;
typedef __attribute__((address_space(3))) unsigned int* lptr_t;
__device__ __forceinline__ void gll16(const void* g, void* l) {
  __builtin_amdgcn_global_load_lds((gptr_t)g, (lptr_t)l, 16, 0, 0);
}

// ---------------- W transpose: [K=1024][N=1024] fp32 -> [N][K] bf16 ----------
__global__ __launch_bounds__(1024) void wt_kernel(const float* __restrict__ Wq,
                                                  const float* __restrict__ Wk,
                                                  const float* __restrict__ Wv,
                                                  unsigned short* __restrict__ wt) {
  const float* W = blockIdx.z == 0 ? Wq : (blockIdx.z == 1 ? Wk : Wv);
  unsigned short* o = wt + (size_t)blockIdx.z * 1048576;
  __shared__ float t[32][33];
  int tx = threadIdx.x, ty = threadIdx.y;
  t[ty][tx] = W[(size_t)(blockIdx.y * 32 + ty) * 1024 + blockIdx.x * 32 + tx];
  __syncthreads();
  o[(size_t)(blockIdx.x * 32 + ty) * 1024 + blockIdx.y * 32 + tx] = f2bf(t[tx][ty]);
}

// ---------------- X fp32 -> bf16 (Q,K,V concatenated) ------------------------
__global__ __launch_bounds__(256) void cvt_kernel(const float* __restrict__ Q,
                                                  const float* __restrict__ K,
                                                  const float* __restrict__ V,
                                                  unsigned short* __restrict__ out) {
  int y = blockIdx.y;
  const float* s = y == 0 ? Q : (y == 1 ? K : V);
  unsigned short* o = out + (size_t)y * 8388608;
  size_t idx = ((size_t)blockIdx.x * 256 + threadIdx.x) * 8;
  float4 f0 = *(const float4*)(s + idx);
  float4 f1 = *(const float4*)(s + idx + 4);
  u32x4 r = {pk2bf(f0.x, f0.y), pk2bf(f0.z, f0.w), pk2bf(f1.x, f1.y), pk2bf(f1.z, f1.w)};
  *(u32x4*)(o + idx) = r;
}

// ---------------- projection GEMM: C[8192,1024] = Xb @ W^T + b ---------------
// m97 main loop; NEW epilogue: LDS-transpose tile -> coalesced b128 stores.
__global__ __launch_bounds__(256) void proj_kernel(
    const unsigned short* __restrict__ Xb, const unsigned short* __restrict__ wt,
    const float* __restrict__ bq, const float* __restrict__ bk, const float* __restrict__ bv,
    unsigned short* __restrict__ qo, unsigned short* __restrict__ ko, unsigned short* __restrict__ vo) {
  int p = blockIdx.z;
  const unsigned short* X = Xb + (size_t)p * 8388608;
  const unsigned short* Wt = wt + (size_t)p * 1048576;
  const float* bias = p == 0 ? bq : (p == 1 ? bk : bv);
  unsigned short* out = p == 0 ? qo : (p == 1 ? ko : vo);

  __shared__ __align__(16) unsigned short smem[16384];  // 32KB
  unsigned short* abuf = smem;
  unsigned short* bbuf = smem + 8192;

  int tid = threadIdx.x;
  int lane = tid & 63, w = tid >> 6;
  int l15 = lane & 15, quad = lane >> 4;
  int wm = w >> 1, wn = w & 1;
  int m0 = blockIdx.x * 128, n0 = blockIdx.y * 128;

  f32x4 acc[4][4] = {};

  for (int kk = 0; kk < 16; ++kk) {
    int k0 = kk * 64;
    for (int j = 0; j < 4; ++j) {
      int stj = w * 4 + j;
      int kt = stj >> 3, t = stj & 7;
      gll16(Wt + (size_t)(n0 + t * 16 + l15) * 1024 + k0 + kt * 32 + quad * 8, &bbuf[stj * 512]);
      gll16(X + (size_t)(m0 + t * 16 + l15) * 1024 + k0 + kt * 32 + quad * 8, &abuf[stj * 512]);
    }
    __syncthreads();
    for (int kt = 0; kt < 2; ++kt) {
      bf16x8 af[4], bfr[4];
      for (int i = 0; i < 4; ++i) af[i]  = *(const bf16x8*)&abuf[(kt * 8 + wm * 4 + i) * 512 + lane * 8];
      for (int j = 0; j < 4; ++j) bfr[j] = *(const bf16x8*)&bbuf[(kt * 8 + wn * 4 + j) * 512 + lane * 8];
      for (int i = 0; i < 4; ++i)
        for (int j = 0; j < 4; ++j)
          acc[i][j] = __builtin_amdgcn_mfma_f32_16x16x32_bf16(af[i], bfr[j], acc[i][j], 0, 0, 0);
    }
    __syncthreads();
  }

  // ---- epilogue: via LDS [lead-local 64][payload 128] stride 136, 2 passes ----
  bool isv = (p == 2);
  int b = m0 >> 11;  // batch (m0 multiple of 128, 2048 | per-batch rows)
  float bl[4];
  for (int j = 0; j < 4; ++j) bl[j] = bias[n0 + wn * 64 + j * 16 + l15];

  __syncthreads();
  for (int p2 = 0; p2 < 2; ++p2) {
    if (!isv) {
      // lead = m. waves with wm==p2 write rows mloc = i*16+quad*4+r, col n.
      if (wm == p2) {
        for (int i = 0; i < 4; ++i)
          for (int j = 0; j < 4; ++j) {
            int col = wn * 64 + j * 16 + l15;
            for (int r = 0; r < 4; ++r) {
              int row = i * 16 + quad * 4 + r;
              smem[row * 136 + col] = f2bf(acc[i][j][r] + bl[j]);
            }
          }
      }
    } else {
      // lead = n. waves with wn==p2 write rows nloc = j*16+l15, col m (pairs).
      if (wn == p2) {
        for (int j = 0; j < 4; ++j) {
          int row = j * 16 + l15;
          for (int i = 0; i < 4; ++i)
            for (int rp = 0; rp < 2; ++rp) {
              int colm = wm * 64 + i * 16 + quad * 4 + rp * 2;
              unsigned u = pk2bf(acc[i][j][rp * 2] + bl[j], acc[i][j][rp * 2 + 1] + bl[j]);
              *(unsigned*)&smem[row * 136 + colm] = u;
            }
        }
      }
    }
    __syncthreads();
    // read: 4 rounds x 256 threads x b128 chunk
    for (int t = 0; t < 4; ++t) {
      int chunk = t * 256 + tid;
      int row = chunk >> 4, cseg = chunk & 15;
      u32x4 v = *(const u32x4*)&smem[row * 136 + cseg * 8];
      size_t idx;
      if (!isv) {
        int m = m0 + p2 * 64 + row;       // s-row
        int s = m & 2047;
        int n = n0 + cseg * 8;            // d-chunk
        int hh = n >> 6, d = n & 63;
        idx = ((size_t)((b * 16 + hh) * 2048 + s) << 6) + d;
      } else {
        int n = n0 + p2 * 64 + row;       // d-row
        int hh = n >> 6, d = n & 63;
        int s = (m0 & 2047) + cseg * 8;   // s-chunk
        idx = ((size_t)((b * 16 + hh) * 64 + d) << 11) + s;
      }
      *(u32x4*)(out + idx) = v;
    }
    __syncthreads();
  }
}

// ---------------- fused attention (32x32x16 MFMA) ---------------------------
// grid (16,16,4), 256 thr = 4 waves, wave owns 32 q-rows.
// S^T = K Q^T (32x32x16): C col=qrow matches 32x32 B-operand n -> P fix-up is
// a lane^32 bpermute exchange + cndmask. O^T = V^T P^T. den via VALU partials.
__global__ __launch_bounds__(256) void attn_kernel(
    const unsigned short* __restrict__ q, const unsigned short* __restrict__ k,
    const unsigned short* __restrict__ vT, const float* __restrict__ mask,
    float* __restrict__ out) {
  int qb = blockIdx.x, hh = blockIdx.y, b = blockIdx.z;
  int tid = threadIdx.x, lane = tid & 63, w = tid >> 6;
  int c = lane & 31, hf = lane >> 5;

  __shared__ __align__(16) unsigned short smem[16384];  // 32KB: K 16KB + V 16KB
  unsigned short* kls = smem;
  unsigned short* vls = smem + 8192;

  const unsigned short* qp = q + (size_t)(b * 16 + hh) * 2048 * 64;
  const unsigned short* kp = k + (size_t)(b * 16 + hh) * 2048 * 64;
  const unsigned short* vp = vT + (size_t)(b * 16 + hh) * 64 * 2048;
  const float* mp = mask + (size_t)b * 2048;

  int q0 = qb * 128 + w * 32;
  // Q B-frags (32x32x16): n=qrow=c, k = sl*16 + hf*8 + j
  bf16x8 qf[4];
  for (int sl = 0; sl < 4; ++sl)
    qf[sl] = *(const bf16x8*)(qp + (size_t)(q0 + c) * 64 + sl * 16 + hf * 8);

  f32x16 oacc[2] = {};  // O^T: dv-tiles; col=qrow, row=dv-local
  float denp = 0.0f;
  int paddr = (lane ^ 32) << 2;
  const float expc = 0.18033688011112042f;  // 0.125 * log2(e)

  for (int kb = 0; kb < 16; ++kb) {
    int kbase = kb * 128;
    __syncthreads();
    for (int j = 0; j < 8; ++j) {
      int st = w * 8 + j;
      if (st < 16) {
        int mt = st >> 2, sl = st & 3;
        gll16(kp + (size_t)(kbase + mt * 32 + c) * 64 + sl * 16 + hf * 8, &kls[st * 512]);
      } else {
        int sv = st - 16;
        int dvt = sv >> 3, ks = sv & 7;
        gll16(vp + (size_t)(dvt * 32 + c) * 2048 + kbase + ks * 16 + hf * 8, &vls[sv * 512]);
      }
    }
    __syncthreads();

    for (int mt = 0; mt < 4; ++mt) {
      // S^T 32x32 tile over keys [mt*32, mt*32+32)
      f32x16 sc = {};
      for (int sl = 0; sl < 4; ++sl) {
        bf16x8 ak = *(const bf16x8*)&kls[(mt * 4 + sl) * 512 + lane * 8];
        sc = __builtin_amdgcn_mfma_f32_32x32x16_bf16(ak, qf[sl], sc, 0, 0, 0);
      }
      // e = exp(S/8)*mask[key]; key = mt*32 + (r&3) + 8*(r>>2) + 4*hf
      unsigned pk[8];
      for (int g = 0; g < 4; ++g) {
        float4 mm = *(const float4*)&mp[kbase + mt * 32 + 8 * g + 4 * hf];
        float e0 = exp2f(sc[4 * g + 0] * expc) * mm.x;
        float e1 = exp2f(sc[4 * g + 1] * expc) * mm.y;
        float e2 = exp2f(sc[4 * g + 2] * expc) * mm.z;
        float e3 = exp2f(sc[4 * g + 3] * expc) * mm.w;
        denp += (e0 + e1) + (e2 + e3);
        pk[2 * g] = pk2bf(e0, e1);
        pk[2 * g + 1] = pk2bf(e2, e3);
      }
      // PV over the 2 16-key slabs of this m-tile
      for (int s = 0; s < 2; ++s) {
        unsigned ta = hf ? pk[4 * s + 0] : pk[4 * s + 2];
        unsigned tb = hf ? pk[4 * s + 1] : pk[4 * s + 3];
        unsigned ba = (unsigned)__builtin_amdgcn_ds_bpermute(paddr, (int)ta);
        unsigned bb = (unsigned)__builtin_amdgcn_ds_bpermute(paddr, (int)tb);
        union { unsigned u[4]; bf16x8 v; } pf;
        pf.u[0] = hf ? ba : pk[4 * s + 0];
        pf.u[1] = hf ? bb : pk[4 * s + 1];
        pf.u[2] = hf ? pk[4 * s + 2] : ba;
        pf.u[3] = hf ? pk[4 * s + 3] : bb;
        int ks = mt * 2 + s;
        for (int dvt = 0; dvt < 2; ++dvt) {
          bf16x8 av = *(const bf16x8*)&vls[(dvt * 8 + ks) * 512 + lane * 8];
          oacc[dvt] = __builtin_amdgcn_mfma_f32_32x32x16_bf16(av, pf.v, oacc[dvt], 0, 0, 0);
        }
      }
    }
  }

  // den: partner exchange (lane^32 holds the other half of the key rows)
  float dpart = __int_as_float(__builtin_amdgcn_ds_bpermute(paddr, __float_as_int(denp)));
  float rden = 1.0f / (denp + dpart + 1e-8f);

  // epilogue: O^T -> O via per-wave LDS transpose (2 passes of 16 qrows)
  __syncthreads();
  float* ew = (float*)smem + w * 2048;  // 8KB per wave
  for (int cp = 0; cp < 2; ++cp) {
    if ((c >> 4) == cp) {
      for (int dvt = 0; dvt < 2; ++dvt)
        for (int r = 0; r < 16; r += 2) {
          int dv = dvt * 32 + (r & 3) + 8 * (r >> 2) + 4 * hf;
          float2 val = make_float2(oacc[dvt][r] * rden, oacc[dvt][r + 1] * rden);
          *(float2*)&ew[(c & 15) * 68 + dv] = val;
        }
    }
    __syncthreads();
    int row = lane >> 2, seg = lane & 3;
    int s = q0 + cp * 16 + row;
    float* op = out + (size_t)(b * 2048 + s) * 1024 + hh * 64 + seg * 16;
    const float* src = &ew[row * 68 + seg * 16];
    for (int i = 0; i < 4; ++i)
      *(float4*)(op + i * 4) = *(const float4*)(src + i * 4);
    __syncthreads();
  }
}

extern "C" void kernel_launch(void* const* d_in, const int* in_sizes, int n_in,
                              void* d_out, int out_size, void* d_ws, size_t ws_size,
                              hipStream_t stream) {
  const float* Q    = (const float*)d_in[0];
  const float* K    = (const float*)d_in[1];
  const float* V    = (const float*)d_in[2];
  const float* mask = (const float*)d_in[3];
  const float* Wq   = (const float*)d_in[4];
  const float* bq   = (const float*)d_in[5];
  const float* Wk   = (const float*)d_in[6];
  const float* bk   = (const float*)d_in[7];
  const float* Wv   = (const float*)d_in[8];
  const float* bv   = (const float*)d_in[9];

  char* ws = (char*)d_ws;
  unsigned short* wt = (unsigned short*)ws;                  // 6MB: 3 x bf16 W^T
  unsigned short* qb = (unsigned short*)(ws + 6291456);      // 16MB [B,H,S,64]
  unsigned short* kb = (unsigned short*)(ws + 23068672);     // 16MB [B,H,S,64]
  unsigned short* vb = (unsigned short*)(ws + 39845888);     // 16MB [B,H,64,S]
  unsigned short* xb = (unsigned short*)(ws + 56623104);     // 48MB bf16 Q,K,V

  hipLaunchKernelGGL(wt_kernel, dim3(32, 32, 3), dim3(32, 32), 0, stream, Wq, Wk, Wv, wt);
  hipLaunchKernelGGL(cvt_kernel, dim3(4096, 3), dim3(256), 0, stream, Q, K, V, xb);
  hipLaunchKernelGGL(proj_kernel, dim3(64, 8, 3), dim3(256), 0, stream,
                     xb, wt, bq, bk, bv, qb, kb, vb);
  hipLaunchKernelGGL(attn_kernel, dim3(16, 16, 4), dim3(256), 0, stream,
                     qb, kb, vb, mask, (float*)d_out);
}